// Round 9
// baseline (24503.773 us; speedup 1.0000x reference)
//
#include <hip/hip_runtime.h>

// ---------------------------------------------------------------------------
// WeatherModel ConvLSTM enc-dec, fp32, MI355X. Round 9: calibrated micro-fixes.
// R8 counters: iattn 358us/43%occ/71%VALU; nb=2 tier. Changes:
// (1) iattn/attn_fuse second-position compute guarded by wave-uniform tid<68
//     (was unguarded: 256 threads paid FMA for 68 useful -> waves 2-3 now skip);
// (2) lstm_dev HCPB 2->4 (288 FMA per 12 LDS reads, was 144; half the blocks);
//     zpart co-block 8->16 (same);
// (3) softmax_mul folded into enc0 dispatch (inline per-pixel softmax on halo
//     + sibling A-update blocks, A double-buffered) -> phase-1 chain 30->20.
// ---------------------------------------------------------------------------

#define PX 16384L   // 128*128
#define T_ 10
#define D_ 10

__device__ __forceinline__ float fast_tanh(float x) {
    const float e = __builtin_exp2f(x * 2.88539008f);          // e^{2x}
    return 1.f - 2.f * __builtin_amdgcn_rcpf(e + 1.f);
}
__device__ __forceinline__ float fast_sig(float x) {
    const float e = __builtin_exp2f(x * -1.44269504f);         // e^{-x}
    return __builtin_amdgcn_rcpf(e + 1.f);
}
__device__ __forceinline__ float fast_exp(float x) {
    return __builtin_exp2f(x * 1.44269504f);
}

// ============ device: fused conv3x3+LSTM gates, 32x16 tile, HCPB=4 =========
// cin = 1 (in0) + 64 (in1). hidden=64. 512 blocks per batch (32 tiles x 16).
__device__ __forceinline__ void lstm_dev(
    float* lds,                        // 8*612 floats
    int tile, int hcb, int b,
    const float* __restrict__ in0, long bs0,
    const float* __restrict__ in1,
    const float* __restrict__ w, const float* __restrict__ bias,
    const float* __restrict__ cprev,
    float* __restrict__ hout, float* __restrict__ cout_)
{
    const int tid = threadIdx.x;
    const int tx = tid & 31, r0 = (tid >> 5) << 1;
    const int tileX = (tile & 3) << 5, tileY = (tile >> 2) << 4;
    const int hc0 = hcb << 2;
    float acc[32];                     // [hc4][g4][rr2]
#pragma unroll
    for (int j = 0; j < 32; j++) acc[j] = 0.f;

    int g0[3]; float m0[3];
#pragma unroll
    for (int i = 0; i < 3; i++) {
        const int lidx = tid + i * 256;
        const int r = lidx / 34, cc = lidx - r * 34;
        const int gy = tileY + r - 1, gx = tileX + cc - 1;
        const bool inb = (lidx < 612) && ((unsigned)gy < 128u) && ((unsigned)gx < 128u);
        g0[i] = inb ? gy * 128 + gx : 0;
        m0[i] = inb ? 1.f : 0.f;
    }

    for (int cb = 0; cb < 65; cb += 8) {
        const int cmax = min(8, 65 - cb);
        for (int cl = 0; cl < cmax; cl++) {
            const int ci = cb + cl;
            const float* p = (ci == 0) ? in0 + (long)b * bs0
                                       : in1 + ((long)b * 64 + (ci - 1)) * PX;
#pragma unroll
            for (int i = 0; i < 3; i++) {
                const int lidx = tid + i * 256;
                if (lidx < 612) lds[cl * 612 + lidx] = m0[i] * p[g0[i]];
            }
        }
        __syncthreads();
        for (int cl = 0; cl < cmax; cl++) {
            float win[4][3];
#pragma unroll
            for (int dy = 0; dy < 4; dy++)
#pragma unroll
                for (int dx = 0; dx < 3; dx++)
                    win[dy][dx] = lds[cl * 612 + (r0 + dy) * 34 + tx + dx];
            const int ci = cb + cl;
#pragma unroll
            for (int j = 0; j < 4; j++)
#pragma unroll
                for (int g = 0; g < 4; g++) {
                    const float* wp = w + ((long)(g * 64 + hc0 + j) * 65 + ci) * 9;
#pragma unroll
                    for (int rr = 0; rr < 2; rr++) {
                        float a = acc[(j * 4 + g) * 2 + rr];
#pragma unroll
                        for (int ky = 0; ky < 3; ky++)
#pragma unroll
                            for (int kx = 0; kx < 3; kx++)
                                a = fmaf(wp[ky * 3 + kx], win[rr + ky][kx], a);
                        acc[(j * 4 + g) * 2 + rr] = a;
                    }
                }
        }
        __syncthreads();
    }
#pragma unroll
    for (int j = 0; j < 4; j++) {
        const int hc = hc0 + j;
        const float bi = bias[hc], bf = bias[64 + hc];
        const float bo = bias[128 + hc], bg = bias[192 + hc];
#pragma unroll
        for (int rr = 0; rr < 2; rr++) {
            const long opix = (long)(tileY + r0 + rr) * 128 + tileX + tx;
            const float i_ = fast_sig(acc[(j * 4 + 0) * 2 + rr] + bi);
            const float f_ = fast_sig(acc[(j * 4 + 1) * 2 + rr] + bf);
            const float o_ = fast_sig(acc[(j * 4 + 2) * 2 + rr] + bo);
            const float g_ = fast_tanh(acc[(j * 4 + 3) * 2 + rr] + bg);
            const float cp = cprev[((long)b * 64 + hc) * PX + opix];
            const float c2 = f_ * cp + i_ * g_;
            const float h2 = o_ * fast_tanh(c2);
            hout[((long)b * 64 + hc) * PX + opix] = h2;
            cout_[((long)b * 64 + hc) * PX + opix] = c2;
        }
    }
}

// ============ device: direct zpart conv (128->32, skip y-ch 0), co=16 ======
__device__ __forceinline__ void zpart_dev(
    float* lds,                        // 4*324 floats
    int tile, int cob, int b,
    const float* __restrict__ hsrc, const float* __restrict__ csrc,
    const float* __restrict__ wt1, const float* __restrict__ bt1,
    float* __restrict__ zdst)
{
    const int tid = threadIdx.x;
    const int tx = tid & 15, ty = tid >> 4;
    const int tileX = (tile & 7) << 4, tileY = (tile >> 3) << 4;
    const int co0 = cob << 4;
    float acc[16];
#pragma unroll
    for (int j = 0; j < 16; j++) acc[j] = 0.f;

    int g0[2]; float m0[2];
#pragma unroll
    for (int i = 0; i < 2; i++) {
        const int lidx = tid + i * 256;
        const int r = lidx / 18, cc = lidx - r * 18;
        const int gy = tileY + r - 1, gx = tileX + cc - 1;
        const bool inb = (lidx < 324) && ((unsigned)gy < 128u) && ((unsigned)gx < 128u);
        g0[i] = inb ? gy * 128 + gx : 0;
        m0[i] = inb ? 1.f : 0.f;
    }

    for (int cb = 0; cb < 128; cb += 4) {
        for (int cl = 0; cl < 4; cl++) {
            const int ci = cb + cl;
            const float* p = (ci < 64) ? hsrc + ((long)b * 64 + ci) * PX
                                       : csrc + ((long)b * 64 + (ci - 64)) * PX;
#pragma unroll
            for (int i = 0; i < 2; i++) {
                const int lidx = tid + i * 256;
                if (lidx < 324) lds[cl * 324 + lidx] = m0[i] * p[g0[i]];
            }
        }
        __syncthreads();
        for (int cl = 0; cl < 4; cl++) {
            float r9[9];
#pragma unroll
            for (int dy = 0; dy < 3; dy++)
#pragma unroll
                for (int dx = 0; dx < 3; dx++)
                    r9[dy * 3 + dx] = lds[cl * 324 + (ty + dy) * 18 + tx + dx];
            const int ci = cb + cl;
#pragma unroll
            for (int j = 0; j < 16; j++) {
                const float* wp = wt1 + ((long)(co0 + j) * 129 + 1 + ci) * 9;
                float a = acc[j];
#pragma unroll
                for (int q = 0; q < 9; q++) a = fmaf(wp[q], r9[q], a);
                acc[j] = a;
            }
        }
        __syncthreads();
    }
    const long opix = (long)(tileY + ty) * 128 + tileX + tx;
#pragma unroll
    for (int j = 0; j < 16; j++)
        zdst[((long)b * 32 + co0 + j) * PX + opix] = acc[j] + bt1[co0 + j];
}

// ============ merged dispatch: conv_lstm (512 blk) [+ zpart (128 blk)] =====
__global__ __launch_bounds__(256)
void lstm_merge_k(const float* __restrict__ in0, long bs0,
                  const float* __restrict__ in1,
                  const float* __restrict__ w, const float* __restrict__ bias,
                  const float* __restrict__ cprev,
                  float* __restrict__ hout, float* __restrict__ cout_,
                  const float* __restrict__ zh, const float* __restrict__ zc,
                  float* __restrict__ zdst,
                  const float* __restrict__ wt1, const float* __restrict__ bt1)
{
    __shared__ float lds[8 * 612];
    const int bid = blockIdx.x, b = blockIdx.z;
    if (bid < 512) {
        lstm_dev(lds, bid & 31, bid >> 5, b, in0, bs0, in1, w, bias,
                 cprev, hout, cout_);
    } else {
        const int q = bid - 512;
        zpart_dev(lds, q & 63, q >> 6, b, zh, zc, wt1, bt1, zdst);
    }
}

// ============ standalone zpart (t=9) =======================================
__global__ __launch_bounds__(256)
void zpart_k(const float* __restrict__ zh, const float* __restrict__ zc,
             float* __restrict__ zdst,
             const float* __restrict__ wt1, const float* __restrict__ bt1)
{
    __shared__ float lds[4 * 324];
    zpart_dev(lds, blockIdx.x, blockIdx.y, blockIdx.z, zh, zc, wt1, bt1, zdst);
}

// ============ merged dispatch: dec-LSTM1 split-K conv [+ zpart(s)] =========
__global__ __launch_bounds__(256)
void dec_merge_k(const float* __restrict__ hs1s,
                 const float* __restrict__ hb1, long hb1bs,
                 const float* __restrict__ w1,          // (4,65,3,3)
                 float* __restrict__ l1p, int nb,
                 const float* __restrict__ zc, float* __restrict__ zdst,
                 const float* __restrict__ wt1, const float* __restrict__ bt1)
{
    __shared__ float lds[4 * 324];
    const int bid = blockIdx.x, b = blockIdx.z;
    if (bid < 256) {
        const int tile = bid & 63, s = bid >> 6;
        const int ci0 = (s == 0) ? 0 : (s == 1) ? 17 : (s == 2) ? 33 : 49;
        const int cn  = (s == 0) ? 17 : 16;
        const int tid = threadIdx.x;
        const int tx = tid & 15, ty = tid >> 4;
        const int tileX = (tile & 7) << 4, tileY = (tile >> 3) << 4;
        int g0[2]; float m0[2];
#pragma unroll
        for (int i = 0; i < 2; i++) {
            const int lidx = tid + i * 256;
            const int r = lidx / 18, cc = lidx - r * 18;
            const int gy = tileY + r - 1, gx = tileX + cc - 1;
            const bool inb = (lidx < 324) && ((unsigned)gy < 128u) && ((unsigned)gx < 128u);
            g0[i] = inb ? gy * 128 + gx : 0;
            m0[i] = inb ? 1.f : 0.f;
        }
        float acc[4] = {0.f, 0.f, 0.f, 0.f};
        for (int cb = 0; cb < cn; cb += 4) {
            const int cmax = min(4, cn - cb);
            for (int cl = 0; cl < cmax; cl++) {
                const int ci = ci0 + cb + cl;
                const float* p = (ci < 64) ? hs1s + ((long)b * 64 + ci) * PX
                                           : hb1 + (long)b * hb1bs;
#pragma unroll
                for (int i = 0; i < 2; i++) {
                    const int lidx = tid + i * 256;
                    if (lidx < 324) lds[cl * 324 + lidx] = m0[i] * p[g0[i]];
                }
            }
            __syncthreads();
            for (int cl = 0; cl < cmax; cl++) {
                float r9[9];
#pragma unroll
                for (int dy = 0; dy < 3; dy++)
#pragma unroll
                    for (int dx = 0; dx < 3; dx++)
                        r9[dy * 3 + dx] = lds[cl * 324 + (ty + dy) * 18 + tx + dx];
                const int ci = ci0 + cb + cl;
#pragma unroll
                for (int j = 0; j < 4; j++) {
                    const float* wp = w1 + ((long)j * 65 + ci) * 9;
                    float a = acc[j];
#pragma unroll
                    for (int q = 0; q < 9; q++) a = fmaf(wp[q], r9[q], a);
                    acc[j] = a;
                }
            }
            __syncthreads();
        }
        const long opix = (long)(tileY + ty) * 128 + tileX + tx;
#pragma unroll
        for (int j = 0; j < 4; j++)
            l1p[(((long)s * nb + b) * 4 + j) * PX + opix] = acc[j];
    } else {
        const int q = bid - 256;
        zpart_dev(lds, q & 63, q >> 6, b, hs1s, zc, wt1, bt1, zdst);
    }
}

// ============ combine split-K LSTM gate partials -> h,c,out2 ===============
__global__ __launch_bounds__(256)
void combine_lstm_k(const float* __restrict__ pbuf, int nsl, int hidden,
                    const float* __restrict__ bias,
                    const float* __restrict__ cprev, long cpbs,
                    float* __restrict__ hout, long hobs,
                    float* __restrict__ cout_, long cobs,
                    float* __restrict__ hout2, long ho2bs, int nb)
{
    const long idx = (long)blockIdx.x * 256 + threadIdx.x;
    if (idx >= (long)nb * hidden * PX) return;
    const long px = idx & 16383;
    const long v = idx >> 14;
    const int hc = (int)(v % hidden), b = (int)(v / hidden);
    const int nco = 4 * hidden;
    float g4[4] = {0.f, 0.f, 0.f, 0.f};
    for (int s = 0; s < nsl; s++)
#pragma unroll
        for (int g = 0; g < 4; g++)
            g4[g] += pbuf[(((long)s * nb + b) * nco + g * hidden + hc) * PX + px];
    const float i_ = fast_sig(g4[0] + bias[hc]);
    const float f_ = fast_sig(g4[1] + bias[hidden + hc]);
    const float o_ = fast_sig(g4[2] + bias[2 * hidden + hc]);
    const float g_ = fast_tanh(g4[3] + bias[3 * hidden + hc]);
    const float cp = cprev[(long)b * cpbs + (long)hc * PX + px];
    const float c2 = f_ * cp + i_ * g_;
    const float h2 = o_ * fast_tanh(c2);
    hout[(long)b * hobs + (long)hc * PX + px] = h2;
    cout_[(long)b * cobs + (long)hc * PX + px] = c2;
    if (hout2) hout2[(long)b * ho2bs + (long)hc * PX + px] = h2;
}

// ============ phase-1 enc0: inline softmax + LSTM, + A-update blocks =======
// grid (128, 1, 8): bid<64 = LSTM tile (computes alpha on its halo inline),
// bid>=64 = elementwise A-update (Anext = Acur * softmax(sc1); Acur==null =>
// just softmax, t=0). Bitwise-identical math to the old softmax_mul+enc0 pair.
__global__ __launch_bounds__(256)
void enc0_lstm_k(const float* __restrict__ x, int t,
                 const float* __restrict__ Acur, float* __restrict__ Anext,
                 const float* __restrict__ sc1,
                 const float* __restrict__ hprev, const float* __restrict__ cprev,
                 const float* __restrict__ w, const float* __restrict__ bias,
                 float* __restrict__ hout, float* __restrict__ cout_)
{
    __shared__ float lds[4 * 324];
    const int tid = threadIdx.x;
    const int b = blockIdx.z;
    if (blockIdx.x >= 64) {
        const long p = (((long)blockIdx.x - 64) << 8) + tid;
        const float* sp = sc1 + (long)b * 10 * PX + p;
        float v[10]; float m = -1e30f;
#pragma unroll
        for (int k = 0; k < 10; k++) { v[k] = sp[k * PX]; m = fmaxf(m, v[k]); }
        float sum = 0.f;
#pragma unroll
        for (int k = 0; k < 10; k++) { v[k] = fast_exp(v[k] - m); sum += v[k]; }
        const float r = __builtin_amdgcn_rcpf(sum);
        float* Ap = Anext + (long)b * 10 * PX + p;
#pragma unroll
        for (int k = 0; k < 10; k++) {
            const float a = v[k] * r;
            Ap[k * PX] = Acur ? Acur[((long)b * 10 + k) * PX + p] * a : a;
        }
        return;
    }
    const int tx = tid & 15, ty = tid >> 4;
    const int tile = blockIdx.x;
    const int tileX = (tile & 7) << 4, tileY = (tile >> 3) << 4;
    int g0[2]; float m0[2]; float e[2][10]; float rr_[2];
#pragma unroll
    for (int i = 0; i < 2; i++) {
        const int lidx = tid + i * 256;
        const int r = lidx / 18, cc = lidx - r * 18;
        const int gy = tileY + r - 1, gx = tileX + cc - 1;
        const bool inb = (lidx < 324) && ((unsigned)gy < 128u) && ((unsigned)gx < 128u);
        g0[i] = inb ? gy * 128 + gx : 0;
        m0[i] = inb ? 1.f : 0.f;
        const float* sp = sc1 + (long)b * 10 * PX + g0[i];
        float mm = -1e30f;
#pragma unroll
        for (int k = 0; k < 10; k++) { e[i][k] = sp[k * PX]; mm = fmaxf(mm, e[i][k]); }
        float sum = 0.f;
#pragma unroll
        for (int k = 0; k < 10; k++) { e[i][k] = fast_exp(e[i][k] - mm); sum += e[i][k]; }
        rr_[i] = __builtin_amdgcn_rcpf(sum);
    }
    float acc[4] = {0.f, 0.f, 0.f, 0.f};
#pragma unroll
    for (int cb = 0; cb < 11; cb += 4) {
#pragma unroll
        for (int cl = 0; cl < 4; cl++) {
            const int ci = cb + cl;
            if (ci < 11) {
#pragma unroll
                for (int i = 0; i < 2; i++) {
                    const int lidx = tid + i * 256;
                    if (lidx < 324) {
                        float vv;
                        if (ci < 10) {
                            float al = e[i][ci] * rr_[i];
                            if (Acur) al *= Acur[((long)b * 10 + ci) * PX + g0[i]];
                            vv = x[(((long)b * T_ + t) * D_ + ci) * PX + g0[i]] * al;
                        } else {
                            vv = hprev[(long)b * PX + g0[i]];
                        }
                        lds[cl * 324 + lidx] = m0[i] * vv;
                    }
                }
            }
        }
        __syncthreads();
#pragma unroll
        for (int cl = 0; cl < 4; cl++) {
            const int ci = cb + cl;
            if (ci < 11) {
                float r9[9];
#pragma unroll
                for (int dy = 0; dy < 3; dy++)
#pragma unroll
                    for (int dx = 0; dx < 3; dx++)
                        r9[dy * 3 + dx] = lds[cl * 324 + (ty + dy) * 18 + tx + dx];
#pragma unroll
                for (int g = 0; g < 4; g++) {
                    const float* wp = w + ((long)g * 11 + ci) * 9;
                    float a = acc[g];
#pragma unroll
                    for (int q = 0; q < 9; q++) a = fmaf(wp[q], r9[q], a);
                    acc[g] = a;
                }
            }
        }
        __syncthreads();
    }
    const long opix = (long)(tileY + ty) * 128 + tileX + tx;
    const float i_ = fast_sig(acc[0] + bias[0]);
    const float f_ = fast_sig(acc[1] + bias[1]);
    const float o_ = fast_sig(acc[2] + bias[2]);
    const float g_ = fast_tanh(acc[3] + bias[3]);
    const float cp = cprev[(long)b * PX + opix];
    const float c2 = f_ * cp + i_ * g_;
    const float h2 = o_ * fast_tanh(c2);
    hout[(long)b * PX + opix] = h2;
    cout_[(long)b * PX + opix] = c2;
}

// ============ fused input-attention score (phase 1, full batch) ============
// A == nullptr => scale 1 (t=0). Second conv1 position only on tid<68 (wave-
// uniform skip for waves 2-3; was unguarded = 40% wasted FMA).
__global__ __launch_bounds__(256)
void iattn_k(const float* __restrict__ x, const float* __restrict__ A,
             const float* __restrict__ h, const float* __restrict__ c,
             const float* __restrict__ wa1, const float* __restrict__ ba1,
             const float* __restrict__ wa2, const float* __restrict__ ba2,
             float* __restrict__ score)
{
    __shared__ float xl[12][400];              // 19.2 KB
    __shared__ float zl[16][324];              // 20.7 KB
    const int tid = threadIdx.x;
    const int tileX = (blockIdx.x & 7) << 4, tileY = (blockIdx.x >> 3) << 4;
    const int z = blockIdx.z;
    const int b = z & 7, k = z >> 3;

    int g0[2]; float m0[2]; float aTr[2];
#pragma unroll
    for (int i = 0; i < 2; i++) {
        const int lidx = tid + i * 256;
        const int r = lidx / 20, cc = lidx - r * 20;
        const int gy = tileY + r - 2, gx = tileX + cc - 2;
        const bool inb = (lidx < 400) && ((unsigned)gy < 128u) && ((unsigned)gx < 128u);
        g0[i] = inb ? gy * 128 + gx : 0;
        m0[i] = inb ? 1.f : 0.f;
        aTr[i] = A ? (m0[i] * A[((long)b * 10 + k) * PX + g0[i]]) : 1.f;
    }
    for (int ch = 0; ch < 12; ch++) {
        const float* p = (ch < 10) ? x + (((long)b * 10 + ch) * 10 + k) * PX
                       : (ch == 10) ? h + (long)b * PX : c + (long)b * PX;
#pragma unroll
        for (int i = 0; i < 2; i++) {
            const int lidx = tid + i * 256;
            if (lidx < 400) {
                float v = m0[i] * p[g0[i]];
                if (ch < 10) v *= aTr[i];
                xl[ch][lidx] = v;
            }
        }
    }
    __syncthreads();

    const int i0 = tid;
    const int i1 = tid + 256;
    const int zr0 = i0 / 18, zc0 = i0 - zr0 * 18;
    const int zr1 = (i1 < 324) ? i1 / 18 : 0;
    const int zc1 = (i1 < 324) ? i1 - zr1 * 18 : 0;
    const int gy0 = tileY + zr0 - 1, gx0 = tileX + zc0 - 1;
    const bool in0_ = ((unsigned)gy0 < 128u) && ((unsigned)gx0 < 128u);
    const int gy1 = tileY + zr1 - 1, gx1 = tileX + zc1 - 1;
    const bool in1_ = (i1 < 324) && ((unsigned)gy1 < 128u) && ((unsigned)gx1 < 128u);

    const int tx = tid & 15, ty = tid >> 4;
    float sacc = ba2[0];

    for (int hf = 0; hf < 2; hf++) {
        float acc0[16];
#pragma unroll
        for (int co = 0; co < 16; co++) acc0[co] = 0.f;
        for (int ci = 0; ci < 12; ci++) {
            float wA[9];
#pragma unroll
            for (int dy = 0; dy < 3; dy++)
#pragma unroll
                for (int dx = 0; dx < 3; dx++)
                    wA[dy * 3 + dx] = xl[ci][(zr0 + dy) * 20 + zc0 + dx];
#pragma unroll
            for (int co = 0; co < 16; co++) {
                const float* wp = wa1 + ((long)(hf * 16 + co) * 12 + ci) * 9;
                float a0 = acc0[co];
#pragma unroll
                for (int q = 0; q < 9; q++) a0 = fmaf(wp[q], wA[q], a0);
                acc0[co] = a0;
            }
        }
        float acc1[16];
        if (tid < 68) {                         // waves 2-3 skip entirely
#pragma unroll
            for (int co = 0; co < 16; co++) acc1[co] = 0.f;
            for (int ci = 0; ci < 12; ci++) {
                float wB[9];
#pragma unroll
                for (int dy = 0; dy < 3; dy++)
#pragma unroll
                    for (int dx = 0; dx < 3; dx++)
                        wB[dy * 3 + dx] = xl[ci][(zr1 + dy) * 20 + zc1 + dx];
#pragma unroll
                for (int co = 0; co < 16; co++) {
                    const float* wp = wa1 + ((long)(hf * 16 + co) * 12 + ci) * 9;
                    float a1 = acc1[co];
#pragma unroll
                    for (int q = 0; q < 9; q++) a1 = fmaf(wp[q], wB[q], a1);
                    acc1[co] = a1;
                }
            }
        }
        if (hf) __syncthreads();   // conv2 of half 0 done before zl overwrite
#pragma unroll
        for (int co = 0; co < 16; co++)
            zl[co][i0] = in0_ ? fast_tanh(acc0[co] + ba1[hf * 16 + co]) : 0.f;
        if (tid < 68) {
#pragma unroll
            for (int co = 0; co < 16; co++)
                zl[co][i1] = in1_ ? fast_tanh(acc1[co] + ba1[hf * 16 + co]) : 0.f;
        }
        __syncthreads();
        for (int co = 0; co < 16; co++) {
            const float* wp = wa2 + (hf * 16 + co) * 9;
#pragma unroll
            for (int ky = 0; ky < 3; ky++)
#pragma unroll
                for (int kx = 0; kx < 3; kx++)
                    sacc = fmaf(wp[ky * 3 + kx], zl[co][(ty + ky) * 18 + tx + kx], sacc);
        }
    }
    score[((long)b * 10 + k) * PX + (long)(tileY + ty) * 128 + tileX + tx] = sacc;
}

// ============ decoder attention score (y-part fused with cached Zpart) =====
__global__ __launch_bounds__(256)
void attn_fuse_k(const float* __restrict__ y, long ybs,
                 const float* __restrict__ zpart,
                 const float* __restrict__ wt1,
                 const float* __restrict__ wt2, const float* __restrict__ bt2,
                 float* __restrict__ score, int nb)
{
    __shared__ float ylds[400];
    __shared__ float zl[16][324];
    const int tid = threadIdx.x;
    const int tileX = (blockIdx.x & 7) << 4, tileY = (blockIdx.x >> 3) << 4;
    const int z = blockIdx.z;
    const int b = z % nb, t = z / nb;

#pragma unroll
    for (int i = 0; i < 2; i++) {
        const int lidx = tid + i * 256;
        if (lidx < 400) {
            const int r = lidx / 20, cc = lidx - r * 20;
            const int gy = tileY + r - 2, gx = tileX + cc - 2;
            const bool inb = ((unsigned)gy < 128u) && ((unsigned)gx < 128u);
            ylds[lidx] = inb ? y[(long)b * ybs + gy * 128 + gx] : 0.f;
        }
    }
    __syncthreads();

    const int i0 = tid, i1 = tid + 256;
    const int zr0 = i0 / 18, zc0 = i0 - zr0 * 18;
    const int zr1 = (i1 < 324) ? i1 / 18 : 0;
    const int zc1 = (i1 < 324) ? i1 - zr1 * 18 : 0;
    const int gy0 = tileY + zr0 - 1, gx0 = tileX + zc0 - 1;
    const bool in0_ = ((unsigned)gy0 < 128u) && ((unsigned)gx0 < 128u);
    const int gy1 = tileY + zr1 - 1, gx1 = tileX + zc1 - 1;
    const bool in1_ = (i1 < 324) && ((unsigned)gy1 < 128u) && ((unsigned)gx1 < 128u);
    const long pix0 = in0_ ? (long)gy0 * 128 + gx0 : 0;
    const long pix1 = in1_ ? (long)gy1 * 128 + gx1 : 0;
    const float* zp0 = zpart + ((long)t * nb + b) * 32 * PX;

    const int tx = tid & 15, ty = tid >> 4;
    float sacc = bt2[0];

    for (int hf = 0; hf < 2; hf++) {
        float yw0[9];
#pragma unroll
        for (int dy = 0; dy < 3; dy++)
#pragma unroll
            for (int dx = 0; dx < 3; dx++)
                yw0[dy * 3 + dx] = ylds[(zr0 + dy) * 20 + zc0 + dx];
        if (hf) __syncthreads();
#pragma unroll 4
        for (int ch = 0; ch < 16; ch++) {
            const int cg = hf * 16 + ch;
            const float* wy = wt1 + (long)cg * 129 * 9;
            float s0 = zp0[(long)cg * PX + pix0];
#pragma unroll
            for (int q = 0; q < 9; q++) s0 = fmaf(wy[q], yw0[q], s0);
            zl[ch][i0] = in0_ ? fast_tanh(s0) : 0.f;
        }
        if (tid < 68) {                        // waves 2-3 skip
            float yw1[9];
#pragma unroll
            for (int dy = 0; dy < 3; dy++)
#pragma unroll
                for (int dx = 0; dx < 3; dx++)
                    yw1[dy * 3 + dx] = ylds[(zr1 + dy) * 20 + zc1 + dx];
#pragma unroll 4
            for (int ch = 0; ch < 16; ch++) {
                const int cg = hf * 16 + ch;
                const float* wy = wt1 + (long)cg * 129 * 9;
                float s1 = zp0[(long)cg * PX + pix1];
#pragma unroll
                for (int q = 0; q < 9; q++) s1 = fmaf(wy[q], yw1[q], s1);
                zl[ch][i1] = in1_ ? fast_tanh(s1) : 0.f;
            }
        }
        __syncthreads();
        for (int ch = 0; ch < 16; ch++) {
            const float* wp = wt2 + (hf * 16 + ch) * 9;
#pragma unroll
            for (int ky = 0; ky < 3; ky++)
#pragma unroll
                for (int kx = 0; kx < 3; kx++)
                    sacc = fmaf(wp[ky * 3 + kx], zl[ch][(ty + ky) * 18 + tx + kx], sacc);
        }
    }
    score[((long)b * 10 + t) * PX + (long)(tileY + ty) * 128 + tileX + tx] = sacc;
}

// ============ fused softmax + temporal weighted sum, ch-group split ========
__global__ __launch_bounds__(256)
void smax_wsum_k(const float* __restrict__ score, const float* __restrict__ hs1,
                 float* __restrict__ aht, int nb)
{
    const long idx = (long)blockIdx.x * 256 + threadIdx.x;
    if (idx >= (long)nb * PX) return;
    const long b = idx >> 14, p = idx & 16383;
    const int ch0 = blockIdx.y * 8;
    const float* base = score + b * 10 * PX + p;
    float v[10]; float m = -1e30f;
#pragma unroll
    for (int t = 0; t < 10; t++) { v[t] = base[t * PX]; m = fmaxf(m, v[t]); }
    float sum = 0.f;
#pragma unroll
    for (int t = 0; t < 10; t++) { v[t] = fast_exp(v[t] - m); sum += v[t]; }
    const float r = __builtin_amdgcn_rcpf(sum);
#pragma unroll
    for (int t = 0; t < 10; t++) v[t] *= r;
    const long slot1 = (long)nb * 64 * PX;
#pragma unroll
    for (int j = 0; j < 8; j++) {
        const int ch = ch0 + j;
        float a = 0.f;
#pragma unroll
        for (int t = 0; t < 10; t++)
            a += v[t] * hs1[t * slot1 + (b * 64 + ch) * PX + p];
        aht[(b * 64 + ch) * PX + p] = a;
    }
}

// ---------------------------------------------------------------------------
extern "C" void kernel_launch(void* const* d_in, const int* in_sizes, int n_in,
                              void* d_out, int out_size, void* d_ws, size_t ws_size,
                              hipStream_t stream)
{
    const float* x      = (const float*)d_in[0];
    const float* h0     = (const float*)d_in[1];
    const float* c0in   = (const float*)d_in[2];
    const float* h1     = (const float*)d_in[3];
    const float* c1     = (const float*)d_in[4];
    const float* w_enc0 = (const float*)d_in[5];
    const float* b_enc0 = (const float*)d_in[6];
    const float* w_enc1 = (const float*)d_in[7];
    const float* b_enc1 = (const float*)d_in[8];
    const float* w_dec0 = (const float*)d_in[9];
    const float* b_dec0 = (const float*)d_in[10];
    const float* w_dec1 = (const float*)d_in[11];
    const float* b_dec1 = (const float*)d_in[12];
    const float* wa1 = (const float*)d_in[13];
    const float* ba1 = (const float*)d_in[14];
    const float* wa2 = (const float*)d_in[15];
    const float* ba2 = (const float*)d_in[16];
    const float* wt1 = (const float*)d_in[17];
    const float* bt1 = (const float*)d_in[18];
    const float* wt2 = (const float*)d_in[19];
    const float* bt2 = (const float*)d_in[20];
    float* out = (float*)d_out;

    // ---- adaptive batch tile: need = (160 + 1188*nb)*PX*4 B ----
    int nb = 0;
    for (int cand = 8; cand >= 1; cand >>= 1) {
        const size_t need = (size_t)(160 + 1188 * cand) * PX * sizeof(float);
        if (need <= ws_size) { nb = cand; break; }
    }
    if (nb == 0) return;

    float* ws = (float*)d_ws;
    float* hs0 = ws;                      // [10][8][PX]
    float* cs0 = hs0 + 80 * PX;           // [10][8][PX]
    float* G   = cs0 + 80 * PX;
    // phase-1 aliases inside G: A double-buffer + scores
    float* Abuf0 = G;                     // [8][10][PX]
    float* Abuf1 = G + 80 * PX;           // [8][10][PX]
    float* sc1   = G + 160 * PX;          // [8][10][PX]
    // phase-2 per-group layout inside G
    const long slot1  = (long)nb * 64 * PX;
    float* hs1   = G;                                 // 10 * slot1
    float* cs1   = hs1 + 10 * slot1;                  // 2 * slot1 (ping-pong)
    float* zpart = cs1 + 2 * slot1;                   // [10][nb][32][PX]
    float* aht   = zpart + (long)10 * nb * 32 * PX;   // [nb][64][PX]
    float* l1p   = aht + (long)nb * 64 * PX;          // [4][nb][4][PX]
    float* hs0g  = l1p + (long)4 * nb * 4 * PX;       // [5][nb][PX]
    float* cs0g  = hs0g + (long)5 * nb * PX;          // [5][nb][PX]
    float* scD   = cs0g + (long)5 * nb * PX;          // [nb][10][PX]

    const dim3 blk(256);
    const long TDP = (long)T_ * D_ * PX;
    const long zslot = (long)nb * 32 * PX;

    // ================= phase 1: encoder layer 0, FULL batch =================
    for (int t = 0; t < 10; t++) {
        const float* hprev = (t == 0) ? h0 : hs0 + (long)(t - 1) * 8 * PX;
        const float* cprev = (t == 0) ? c0in : cs0 + (long)(t - 1) * 8 * PX;
        const float* Acur  = (t == 0) ? nullptr : ((t & 1) ? Abuf1 : Abuf0);
        float* Anext = (t & 1) ? Abuf0 : Abuf1;
        iattn_k<<<dim3(64, 1, 80), blk, 0, stream>>>(
            x, Acur, hprev, cprev, wa1, ba1, wa2, ba2, sc1);
        enc0_lstm_k<<<dim3(128, 1, 8), blk, 0, stream>>>(
            x, t, Acur, Anext, sc1, hprev, cprev, w_enc0, b_enc0,
            hs0 + (long)t * 8 * PX, cs0 + (long)t * 8 * PX);
    }

    // ================= phase 2: per batch-group =================
    for (int b0 = 0; b0 < 8; b0 += nb) {
        const float* xb  = x + (long)b0 * TDP;
        float* outb = out + (long)b0 * 5 * PX;

        // -------- encoder layer 1, with zpart(t-1) merged in ---------------
        for (int t = 0; t < 10; t++) {
            const float* hprev = (t == 0) ? h1 + (long)b0 * 64 * PX
                                          : hs1 + (long)(t - 1) * slot1;
            const float* cprev = (t == 0) ? c1 + (long)b0 * 64 * PX
                                          : cs1 + (long)((t - 1) & 1) * slot1;
            const int gx = (t == 0) ? 512 : 640;
            lstm_merge_k<<<dim3(gx, 1, nb), blk, 0, stream>>>(
                hs0 + (long)t * 8 * PX + (long)b0 * PX, PX,
                hprev, w_enc1, b_enc1, cprev,
                hs1 + (long)t * slot1, cs1 + (long)(t & 1) * slot1,
                (t == 0) ? nullptr : hs1 + (long)(t - 1) * slot1,
                (t == 0) ? nullptr : cs1 + (long)((t - 1) & 1) * slot1,
                (t == 0) ? nullptr : zpart + (long)(t - 1) * zslot,
                wt1, bt1);
        }
        zpart_k<<<dim3(64, 2, nb), blk, 0, stream>>>(
            hs1 + 9L * slot1, cs1 + slot1, zpart + 9L * zslot, wt1, bt1);

        // -------- decoder (5 steps) --------
        for (int s = 0; s < 5; s++) {
            const float* yptr; long ybs;
            if (s == 0) { yptr = xb + 9L * D_ * PX; ybs = TDP; }
            else        { yptr = hs0g + (long)(s - 1) * nb * PX; ybs = PX; }
            const float* hb1 = (s == 0) ? hs0 + 9L * 8 * PX + (long)b0 * PX
                                        : hs0g + (long)(s - 1) * nb * PX;
            const float* cb1 = (s == 0) ? cs0 + 9L * 8 * PX + (long)b0 * PX
                                        : cs0g + (long)(s - 1) * nb * PX;

            attn_fuse_k<<<dim3(64, 1, 10 * nb), blk, 0, stream>>>(
                yptr, ybs, zpart, wt1, wt2, bt2, scD, nb);
            smax_wsum_k<<<dim3((int)(((long)nb * PX + 255) / 256), 8), blk, 0, stream>>>(
                scD, hs1, aht, nb);

            // decoder LSTM 0 (no merged zpart: it depends on this kernel)
            lstm_merge_k<<<dim3(512, 1, nb), blk, 0, stream>>>(
                yptr, ybs, aht, w_dec0, b_dec0,
                cs1 + (long)((s + 1) & 1) * slot1,
                hs1 + (long)s * slot1, cs1 + (long)(s & 1) * slot1,
                nullptr, nullptr, nullptr, wt1, bt1);

            // dec LSTM1 split-K conv + zpart(s) (skip zpart at s=4)
            const int gx2 = (s < 4) ? 384 : 256;
            dec_merge_k<<<dim3(gx2, 1, nb), blk, 0, stream>>>(
                hs1 + (long)s * slot1, hb1, PX, w_dec1, l1p, nb,
                cs1 + (long)(s & 1) * slot1, zpart + (long)s * zslot, wt1, bt1);
            combine_lstm_k<<<(int)(((long)nb * PX + 255) / 256), blk, 0, stream>>>(
                l1p, 4, 1, b_dec1, cb1, PX,
                hs0g + (long)s * nb * PX, PX,
                cs0g + (long)s * nb * PX, PX,
                outb + (long)s * PX, 5 * PX, nb);
        }
    }
}

// Round 10
// 18882.016 us; speedup vs baseline: 1.2977x; 1.2977x over previous
//
#include <hip/hip_runtime.h>

// ---------------------------------------------------------------------------
// WeatherModel ConvLSTM enc-dec, fp32, MI355X. Round 10: revert R9 (guard +
// HCPB=4 regressed: serializing parallel-redundant work hurts in this
// latency-bound regime). Base = R8 (21.9 ms). New: (a) nb tiers
// {8,6,5,4,3,2,1} + remainder groups (probes ws_size upward, zero risk);
// (b) iattn zl 16->8 ch (LDS 39.9->29.6KB -> 5 blocks/CU), R8 structure kept.
// ---------------------------------------------------------------------------

#define PX 16384L   // 128*128
#define T_ 10
#define D_ 10

__device__ __forceinline__ float fast_tanh(float x) {
    const float e = __builtin_exp2f(x * 2.88539008f);          // e^{2x}
    return 1.f - 2.f * __builtin_amdgcn_rcpf(e + 1.f);
}
__device__ __forceinline__ float fast_sig(float x) {
    const float e = __builtin_exp2f(x * -1.44269504f);         // e^{-x}
    return __builtin_amdgcn_rcpf(e + 1.f);
}
__device__ __forceinline__ float fast_exp(float x) {
    return __builtin_exp2f(x * 1.44269504f);
}

// ============ device: fused conv3x3+LSTM gates, 32x16 tile, HCPB=2 =========
__device__ __forceinline__ void lstm_dev(
    float* lds,                        // 8*612 floats
    int tile, int hcb, int b,
    const float* __restrict__ in0, long bs0,
    const float* __restrict__ in1,
    const float* __restrict__ w, const float* __restrict__ bias,
    const float* __restrict__ cprev,
    float* __restrict__ hout, float* __restrict__ cout_)
{
    const int tid = threadIdx.x;
    const int tx = tid & 31, r0 = (tid >> 5) << 1;
    const int tileX = (tile & 3) << 5, tileY = (tile >> 2) << 4;
    const int hc0 = hcb << 1;
    float acc[16];                     // [hc2][g4][rr2]
#pragma unroll
    for (int j = 0; j < 16; j++) acc[j] = 0.f;

    int g0[3]; float m0[3];
#pragma unroll
    for (int i = 0; i < 3; i++) {
        const int lidx = tid + i * 256;
        const int r = lidx / 34, cc = lidx - r * 34;
        const int gy = tileY + r - 1, gx = tileX + cc - 1;
        const bool inb = (lidx < 612) && ((unsigned)gy < 128u) && ((unsigned)gx < 128u);
        g0[i] = inb ? gy * 128 + gx : 0;
        m0[i] = inb ? 1.f : 0.f;
    }

    for (int cb = 0; cb < 65; cb += 8) {
        const int cmax = min(8, 65 - cb);
        for (int cl = 0; cl < cmax; cl++) {
            const int ci = cb + cl;
            const float* p = (ci == 0) ? in0 + (long)b * bs0
                                       : in1 + ((long)b * 64 + (ci - 1)) * PX;
#pragma unroll
            for (int i = 0; i < 3; i++) {
                const int lidx = tid + i * 256;
                if (lidx < 612) lds[cl * 612 + lidx] = m0[i] * p[g0[i]];
            }
        }
        __syncthreads();
        for (int cl = 0; cl < cmax; cl++) {
            float win[4][3];
#pragma unroll
            for (int dy = 0; dy < 4; dy++)
#pragma unroll
                for (int dx = 0; dx < 3; dx++)
                    win[dy][dx] = lds[cl * 612 + (r0 + dy) * 34 + tx + dx];
            const int ci = cb + cl;
#pragma unroll
            for (int j = 0; j < 2; j++)
#pragma unroll
                for (int g = 0; g < 4; g++) {
                    const float* wp = w + ((long)(g * 64 + hc0 + j) * 65 + ci) * 9;
#pragma unroll
                    for (int rr = 0; rr < 2; rr++) {
                        float a = acc[(j * 4 + g) * 2 + rr];
#pragma unroll
                        for (int ky = 0; ky < 3; ky++)
#pragma unroll
                            for (int kx = 0; kx < 3; kx++)
                                a = fmaf(wp[ky * 3 + kx], win[rr + ky][kx], a);
                        acc[(j * 4 + g) * 2 + rr] = a;
                    }
                }
        }
        __syncthreads();
    }
#pragma unroll
    for (int j = 0; j < 2; j++) {
        const int hc = hc0 + j;
        const float bi = bias[hc], bf = bias[64 + hc];
        const float bo = bias[128 + hc], bg = bias[192 + hc];
#pragma unroll
        for (int rr = 0; rr < 2; rr++) {
            const long opix = (long)(tileY + r0 + rr) * 128 + tileX + tx;
            const float i_ = fast_sig(acc[(j * 4 + 0) * 2 + rr] + bi);
            const float f_ = fast_sig(acc[(j * 4 + 1) * 2 + rr] + bf);
            const float o_ = fast_sig(acc[(j * 4 + 2) * 2 + rr] + bo);
            const float g_ = fast_tanh(acc[(j * 4 + 3) * 2 + rr] + bg);
            const float cp = cprev[((long)b * 64 + hc) * PX + opix];
            const float c2 = f_ * cp + i_ * g_;
            const float h2 = o_ * fast_tanh(c2);
            hout[((long)b * 64 + hc) * PX + opix] = h2;
            cout_[((long)b * 64 + hc) * PX + opix] = c2;
        }
    }
}

// ============ device: direct zpart conv (128->32, skip y-ch 0), co=8 =======
__device__ __forceinline__ void zpart_dev(
    float* lds,                        // 4*324 floats
    int tile, int cob, int b,
    const float* __restrict__ hsrc, const float* __restrict__ csrc,
    const float* __restrict__ wt1, const float* __restrict__ bt1,
    float* __restrict__ zdst)
{
    const int tid = threadIdx.x;
    const int tx = tid & 15, ty = tid >> 4;
    const int tileX = (tile & 7) << 4, tileY = (tile >> 3) << 4;
    const int co0 = cob << 3;
    float acc[8];
#pragma unroll
    for (int j = 0; j < 8; j++) acc[j] = 0.f;

    int g0[2]; float m0[2];
#pragma unroll
    for (int i = 0; i < 2; i++) {
        const int lidx = tid + i * 256;
        const int r = lidx / 18, cc = lidx - r * 18;
        const int gy = tileY + r - 1, gx = tileX + cc - 1;
        const bool inb = (lidx < 324) && ((unsigned)gy < 128u) && ((unsigned)gx < 128u);
        g0[i] = inb ? gy * 128 + gx : 0;
        m0[i] = inb ? 1.f : 0.f;
    }

    for (int cb = 0; cb < 128; cb += 4) {
        for (int cl = 0; cl < 4; cl++) {
            const int ci = cb + cl;
            const float* p = (ci < 64) ? hsrc + ((long)b * 64 + ci) * PX
                                       : csrc + ((long)b * 64 + (ci - 64)) * PX;
#pragma unroll
            for (int i = 0; i < 2; i++) {
                const int lidx = tid + i * 256;
                if (lidx < 324) lds[cl * 324 + lidx] = m0[i] * p[g0[i]];
            }
        }
        __syncthreads();
        for (int cl = 0; cl < 4; cl++) {
            float r9[9];
#pragma unroll
            for (int dy = 0; dy < 3; dy++)
#pragma unroll
                for (int dx = 0; dx < 3; dx++)
                    r9[dy * 3 + dx] = lds[cl * 324 + (ty + dy) * 18 + tx + dx];
            const int ci = cb + cl;
#pragma unroll
            for (int j = 0; j < 8; j++) {
                const float* wp = wt1 + ((long)(co0 + j) * 129 + 1 + ci) * 9;
                float a = acc[j];
#pragma unroll
                for (int q = 0; q < 9; q++) a = fmaf(wp[q], r9[q], a);
                acc[j] = a;
            }
        }
        __syncthreads();
    }
    const long opix = (long)(tileY + ty) * 128 + tileX + tx;
#pragma unroll
    for (int j = 0; j < 8; j++)
        zdst[((long)b * 32 + co0 + j) * PX + opix] = acc[j] + bt1[co0 + j];
}

// ============ merged dispatch: conv_lstm (1024 blk) [+ zpart (256 blk)] ====
__global__ __launch_bounds__(256)
void lstm_merge_k(const float* __restrict__ in0, long bs0,
                  const float* __restrict__ in1,
                  const float* __restrict__ w, const float* __restrict__ bias,
                  const float* __restrict__ cprev,
                  float* __restrict__ hout, float* __restrict__ cout_,
                  const float* __restrict__ zh, const float* __restrict__ zc,
                  float* __restrict__ zdst,
                  const float* __restrict__ wt1, const float* __restrict__ bt1)
{
    __shared__ float lds[8 * 612];
    const int bid = blockIdx.x, b = blockIdx.z;
    if (bid < 1024) {
        lstm_dev(lds, bid & 31, bid >> 5, b, in0, bs0, in1, w, bias,
                 cprev, hout, cout_);
    } else {
        const int q = bid - 1024;
        zpart_dev(lds, q & 63, q >> 6, b, zh, zc, wt1, bt1, zdst);
    }
}

// ============ standalone zpart (t=9) =======================================
__global__ __launch_bounds__(256)
void zpart_k(const float* __restrict__ zh, const float* __restrict__ zc,
             float* __restrict__ zdst,
             const float* __restrict__ wt1, const float* __restrict__ bt1)
{
    __shared__ float lds[4 * 324];
    zpart_dev(lds, blockIdx.x, blockIdx.y, blockIdx.z, zh, zc, wt1, bt1, zdst);
}

// ============ merged dispatch: dec-LSTM1 split-K conv [+ zpart(s)] =========
// nbs = layout batch-stride count (launch z-extent may be rb < nbs).
__global__ __launch_bounds__(256)
void dec_merge_k(const float* __restrict__ hs1s,
                 const float* __restrict__ hb1, long hb1bs,
                 const float* __restrict__ w1,          // (4,65,3,3)
                 float* __restrict__ l1p, int nbs,
                 const float* __restrict__ zc, float* __restrict__ zdst,
                 const float* __restrict__ wt1, const float* __restrict__ bt1)
{
    __shared__ float lds[4 * 324];
    const int bid = blockIdx.x, b = blockIdx.z;
    if (bid < 256) {
        const int tile = bid & 63, s = bid >> 6;
        const int ci0 = (s == 0) ? 0 : (s == 1) ? 17 : (s == 2) ? 33 : 49;
        const int cn  = (s == 0) ? 17 : 16;
        const int tid = threadIdx.x;
        const int tx = tid & 15, ty = tid >> 4;
        const int tileX = (tile & 7) << 4, tileY = (tile >> 3) << 4;
        int g0[2]; float m0[2];
#pragma unroll
        for (int i = 0; i < 2; i++) {
            const int lidx = tid + i * 256;
            const int r = lidx / 18, cc = lidx - r * 18;
            const int gy = tileY + r - 1, gx = tileX + cc - 1;
            const bool inb = (lidx < 324) && ((unsigned)gy < 128u) && ((unsigned)gx < 128u);
            g0[i] = inb ? gy * 128 + gx : 0;
            m0[i] = inb ? 1.f : 0.f;
        }
        float acc[4] = {0.f, 0.f, 0.f, 0.f};
        for (int cb = 0; cb < cn; cb += 4) {
            const int cmax = min(4, cn - cb);
            for (int cl = 0; cl < cmax; cl++) {
                const int ci = ci0 + cb + cl;
                const float* p = (ci < 64) ? hs1s + ((long)b * 64 + ci) * PX
                                           : hb1 + (long)b * hb1bs;
#pragma unroll
                for (int i = 0; i < 2; i++) {
                    const int lidx = tid + i * 256;
                    if (lidx < 324) lds[cl * 324 + lidx] = m0[i] * p[g0[i]];
                }
            }
            __syncthreads();
            for (int cl = 0; cl < cmax; cl++) {
                float r9[9];
#pragma unroll
                for (int dy = 0; dy < 3; dy++)
#pragma unroll
                    for (int dx = 0; dx < 3; dx++)
                        r9[dy * 3 + dx] = lds[cl * 324 + (ty + dy) * 18 + tx + dx];
                const int ci = ci0 + cb + cl;
#pragma unroll
                for (int j = 0; j < 4; j++) {
                    const float* wp = w1 + ((long)j * 65 + ci) * 9;
                    float a = acc[j];
#pragma unroll
                    for (int q = 0; q < 9; q++) a = fmaf(wp[q], r9[q], a);
                    acc[j] = a;
                }
            }
            __syncthreads();
        }
        const long opix = (long)(tileY + ty) * 128 + tileX + tx;
#pragma unroll
        for (int j = 0; j < 4; j++)
            l1p[(((long)s * nbs + b) * 4 + j) * PX + opix] = acc[j];
    } else {
        const int q = bid - 256;
        zpart_dev(lds, q & 63, q >> 6, b, hs1s, zc, wt1, bt1, zdst);
    }
}

// ============ combine split-K LSTM gate partials -> h,c,out2 ===============
__global__ __launch_bounds__(256)
void combine_lstm_k(const float* __restrict__ pbuf, int nsl, int hidden,
                    const float* __restrict__ bias,
                    const float* __restrict__ cprev, long cpbs,
                    float* __restrict__ hout, long hobs,
                    float* __restrict__ cout_, long cobs,
                    float* __restrict__ hout2, long ho2bs, int rb, int nbs)
{
    const long idx = (long)blockIdx.x * 256 + threadIdx.x;
    if (idx >= (long)rb * hidden * PX) return;
    const long px = idx & 16383;
    const long v = idx >> 14;
    const int hc = (int)(v % hidden), b = (int)(v / hidden);
    const int nco = 4 * hidden;
    float g4[4] = {0.f, 0.f, 0.f, 0.f};
    for (int s = 0; s < nsl; s++)
#pragma unroll
        for (int g = 0; g < 4; g++)
            g4[g] += pbuf[(((long)s * nbs + b) * nco + g * hidden + hc) * PX + px];
    const float i_ = fast_sig(g4[0] + bias[hc]);
    const float f_ = fast_sig(g4[1] + bias[hidden + hc]);
    const float o_ = fast_sig(g4[2] + bias[2 * hidden + hc]);
    const float g_ = fast_tanh(g4[3] + bias[3 * hidden + hc]);
    const float cp = cprev[(long)b * cpbs + (long)hc * PX + px];
    const float c2 = f_ * cp + i_ * g_;
    const float h2 = o_ * fast_tanh(c2);
    hout[(long)b * hobs + (long)hc * PX + px] = h2;
    cout_[(long)b * cobs + (long)hc * PX + px] = c2;
    if (hout2) hout2[(long)b * ho2bs + (long)hc * PX + px] = h2;
}

// ============ phase-1 enc0 LSTM: direct fused conv (11 ch) + gates =========
__global__ __launch_bounds__(256)
void enc0_lstm_k(const float* __restrict__ x, int t, const float* __restrict__ A,
                 const float* __restrict__ hprev, const float* __restrict__ cprev,
                 const float* __restrict__ w, const float* __restrict__ bias,
                 float* __restrict__ hout, float* __restrict__ cout_)
{
    __shared__ float lds[4 * 324];
    const int tid = threadIdx.x;
    const int tx = tid & 15, ty = tid >> 4;
    const int tile = blockIdx.x, b = blockIdx.z;
    const int tileX = (tile & 7) << 4, tileY = (tile >> 3) << 4;
    int g0[2]; float m0[2];
#pragma unroll
    for (int i = 0; i < 2; i++) {
        const int lidx = tid + i * 256;
        const int r = lidx / 18, cc = lidx - r * 18;
        const int gy = tileY + r - 1, gx = tileX + cc - 1;
        const bool inb = (lidx < 324) && ((unsigned)gy < 128u) && ((unsigned)gx < 128u);
        g0[i] = inb ? gy * 128 + gx : 0;
        m0[i] = inb ? 1.f : 0.f;
    }
    float acc[4] = {0.f, 0.f, 0.f, 0.f};
    for (int cb = 0; cb < 11; cb += 4) {
        const int cmax = min(4, 11 - cb);
        for (int cl = 0; cl < cmax; cl++) {
            const int ci = cb + cl;
#pragma unroll
            for (int i = 0; i < 2; i++) {
                const int lidx = tid + i * 256;
                if (lidx < 324) {
                    float v;
                    if (ci < 10) {
                        v = x[(((long)b * T_ + t) * D_ + ci) * PX + g0[i]]
                            * A[((long)b * 10 + ci) * PX + g0[i]];
                    } else {
                        v = hprev[(long)b * PX + g0[i]];
                    }
                    lds[cl * 324 + lidx] = m0[i] * v;
                }
            }
        }
        __syncthreads();
        for (int cl = 0; cl < cmax; cl++) {
            float r9[9];
#pragma unroll
            for (int dy = 0; dy < 3; dy++)
#pragma unroll
                for (int dx = 0; dx < 3; dx++)
                    r9[dy * 3 + dx] = lds[cl * 324 + (ty + dy) * 18 + tx + dx];
            const int ci = cb + cl;
#pragma unroll
            for (int g = 0; g < 4; g++) {
                const float* wp = w + ((long)g * 11 + ci) * 9;
                float a = acc[g];
#pragma unroll
                for (int q = 0; q < 9; q++) a = fmaf(wp[q], r9[q], a);
                acc[g] = a;
            }
        }
        __syncthreads();
    }
    const long opix = (long)(tileY + ty) * 128 + tileX + tx;
    const float i_ = fast_sig(acc[0] + bias[0]);
    const float f_ = fast_sig(acc[1] + bias[1]);
    const float o_ = fast_sig(acc[2] + bias[2]);
    const float g_ = fast_tanh(acc[3] + bias[3]);
    const float cp = cprev[(long)b * PX + opix];
    const float c2 = f_ * cp + i_ * g_;
    const float h2 = o_ * fast_tanh(c2);
    hout[(long)b * PX + opix] = h2;
    cout_[(long)b * PX + opix] = c2;
}

// ============ fused input-attention score (phase 1, full batch) ============
// A == nullptr => scale 1 (t=0). R8 structure (all threads compute both
// positions — parallel-redundant on purpose); zl 8 ch x 4 quarters -> 29.6KB.
__global__ __launch_bounds__(256)
void iattn_k(const float* __restrict__ x, const float* __restrict__ A,
             const float* __restrict__ h, const float* __restrict__ c,
             const float* __restrict__ wa1, const float* __restrict__ ba1,
             const float* __restrict__ wa2, const float* __restrict__ ba2,
             float* __restrict__ score)
{
    __shared__ float xl[12][400];              // 19.2 KB
    __shared__ float zl[8][324];               // 10.4 KB
    const int tid = threadIdx.x;
    const int tileX = (blockIdx.x & 7) << 4, tileY = (blockIdx.x >> 3) << 4;
    const int z = blockIdx.z;
    const int b = z & 7, k = z >> 3;

    int g0[2]; float m0[2]; float aTr[2];
#pragma unroll
    for (int i = 0; i < 2; i++) {
        const int lidx = tid + i * 256;
        const int r = lidx / 20, cc = lidx - r * 20;
        const int gy = tileY + r - 2, gx = tileX + cc - 2;
        const bool inb = (lidx < 400) && ((unsigned)gy < 128u) && ((unsigned)gx < 128u);
        g0[i] = inb ? gy * 128 + gx : 0;
        m0[i] = inb ? 1.f : 0.f;
        aTr[i] = A ? (m0[i] * A[((long)b * 10 + k) * PX + g0[i]]) : 1.f;
    }
    for (int ch = 0; ch < 12; ch++) {
        const float* p = (ch < 10) ? x + (((long)b * 10 + ch) * 10 + k) * PX
                       : (ch == 10) ? h + (long)b * PX : c + (long)b * PX;
#pragma unroll
        for (int i = 0; i < 2; i++) {
            const int lidx = tid + i * 256;
            if (lidx < 400) {
                float v = m0[i] * p[g0[i]];
                if (ch < 10) v *= aTr[i];
                xl[ch][lidx] = v;
            }
        }
    }
    __syncthreads();

    const int i0 = tid;
    const int i1 = tid + 256;
    const int zr0 = i0 / 18, zc0 = i0 - zr0 * 18;
    const int zr1 = (i1 < 324) ? i1 / 18 : 0;
    const int zc1 = (i1 < 324) ? i1 - zr1 * 18 : 0;
    const int gy0 = tileY + zr0 - 1, gx0 = tileX + zc0 - 1;
    const bool in0_ = ((unsigned)gy0 < 128u) && ((unsigned)gx0 < 128u);
    const int gy1 = tileY + zr1 - 1, gx1 = tileX + zc1 - 1;
    const bool in1_ = (i1 < 324) && ((unsigned)gy1 < 128u) && ((unsigned)gx1 < 128u);

    const int tx = tid & 15, ty = tid >> 4;
    float sacc = ba2[0];

    for (int hf = 0; hf < 4; hf++) {
        float acc0[8], acc1[8];
#pragma unroll
        for (int co = 0; co < 8; co++) { acc0[co] = 0.f; acc1[co] = 0.f; }
        for (int ci = 0; ci < 12; ci++) {
            float wA[9], wB[9];
#pragma unroll
            for (int dy = 0; dy < 3; dy++)
#pragma unroll
                for (int dx = 0; dx < 3; dx++) {
                    wA[dy * 3 + dx] = xl[ci][(zr0 + dy) * 20 + zc0 + dx];
                    wB[dy * 3 + dx] = xl[ci][(zr1 + dy) * 20 + zc1 + dx];
                }
#pragma unroll
            for (int co = 0; co < 8; co++) {
                const float* wp = wa1 + ((long)(hf * 8 + co) * 12 + ci) * 9;
                float a0 = acc0[co], a1 = acc1[co];
#pragma unroll
                for (int q = 0; q < 9; q++) {
                    a0 = fmaf(wp[q], wA[q], a0);
                    a1 = fmaf(wp[q], wB[q], a1);
                }
                acc0[co] = a0; acc1[co] = a1;
            }
        }
        if (hf) __syncthreads();   // previous quarter's conv2 reads done
#pragma unroll
        for (int co = 0; co < 8; co++) {
            zl[co][i0] = in0_ ? fast_tanh(acc0[co] + ba1[hf * 8 + co]) : 0.f;
            if (i1 < 324) zl[co][i1] = in1_ ? fast_tanh(acc1[co] + ba1[hf * 8 + co]) : 0.f;
        }
        __syncthreads();
        for (int co = 0; co < 8; co++) {
            const float* wp = wa2 + (hf * 8 + co) * 9;
#pragma unroll
            for (int ky = 0; ky < 3; ky++)
#pragma unroll
                for (int kx = 0; kx < 3; kx++)
                    sacc = fmaf(wp[ky * 3 + kx], zl[co][(ty + ky) * 18 + tx + kx], sacc);
        }
    }
    score[((long)b * 10 + k) * PX + (long)(tileY + ty) * 128 + tileX + tx] = sacc;
}

// ============ softmax over 10 (+compound into A) ===========================
__global__ __launch_bounds__(256)
void softmax_mul_k(const float* __restrict__ s, float* __restrict__ A, int nb, int init)
{
    const long idx = (long)blockIdx.x * 256 + threadIdx.x;
    if (idx >= (long)nb * PX) return;
    const long b = idx >> 14, p = idx & 16383;
    const float* base = s + b * 10 * PX + p;
    float v[10]; float m = -1e30f;
#pragma unroll
    for (int t = 0; t < 10; t++) { v[t] = base[t * PX]; m = fmaxf(m, v[t]); }
    float sum = 0.f;
#pragma unroll
    for (int t = 0; t < 10; t++) { v[t] = fast_exp(v[t] - m); sum += v[t]; }
    const float r = __builtin_amdgcn_rcpf(sum);
    float* Ab = A + b * 10 * PX + p;
#pragma unroll
    for (int t = 0; t < 10; t++)
        Ab[t * PX] = init ? (v[t] * r) : (Ab[t * PX] * v[t] * r);
}

// ============ decoder attention score (y-part fused with cached Zpart) =====
// R8 structure (both positions on all threads). rb = live batches, nbs = stride.
__global__ __launch_bounds__(256)
void attn_fuse_k(const float* __restrict__ y, long ybs,
                 const float* __restrict__ zpart,
                 const float* __restrict__ wt1,
                 const float* __restrict__ wt2, const float* __restrict__ bt2,
                 float* __restrict__ score, int rb, int nbs)
{
    __shared__ float ylds[400];
    __shared__ float zl[16][324];
    const int tid = threadIdx.x;
    const int tileX = (blockIdx.x & 7) << 4, tileY = (blockIdx.x >> 3) << 4;
    const int z = blockIdx.z;
    const int b = z % rb, t = z / rb;

#pragma unroll
    for (int i = 0; i < 2; i++) {
        const int lidx = tid + i * 256;
        if (lidx < 400) {
            const int r = lidx / 20, cc = lidx - r * 20;
            const int gy = tileY + r - 2, gx = tileX + cc - 2;
            const bool inb = ((unsigned)gy < 128u) && ((unsigned)gx < 128u);
            ylds[lidx] = inb ? y[(long)b * ybs + gy * 128 + gx] : 0.f;
        }
    }
    __syncthreads();

    const int i0 = tid, i1 = tid + 256;
    const int zr0 = i0 / 18, zc0 = i0 - zr0 * 18;
    const int zr1 = (i1 < 324) ? i1 / 18 : 0;
    const int zc1 = (i1 < 324) ? i1 - zr1 * 18 : 0;
    const int gy0 = tileY + zr0 - 1, gx0 = tileX + zc0 - 1;
    const bool in0_ = ((unsigned)gy0 < 128u) && ((unsigned)gx0 < 128u);
    const int gy1 = tileY + zr1 - 1, gx1 = tileX + zc1 - 1;
    const bool in1_ = (i1 < 324) && ((unsigned)gy1 < 128u) && ((unsigned)gx1 < 128u);
    const long pix0 = in0_ ? (long)gy0 * 128 + gx0 : 0;
    const long pix1 = in1_ ? (long)gy1 * 128 + gx1 : 0;
    const float* zp0 = zpart + ((long)t * nbs + b) * 32 * PX;

    const int tx = tid & 15, ty = tid >> 4;
    float sacc = bt2[0];

    for (int hf = 0; hf < 2; hf++) {
        float yw0[9], yw1[9];
#pragma unroll
        for (int dy = 0; dy < 3; dy++)
#pragma unroll
            for (int dx = 0; dx < 3; dx++) {
                yw0[dy * 3 + dx] = ylds[(zr0 + dy) * 20 + zc0 + dx];
                yw1[dy * 3 + dx] = ylds[(zr1 + dy) * 20 + zc1 + dx];
            }
        if (hf) __syncthreads();
#pragma unroll 4
        for (int ch = 0; ch < 16; ch++) {
            const int cg = hf * 16 + ch;
            const float* wy = wt1 + (long)cg * 129 * 9;
            float s0 = zp0[(long)cg * PX + pix0];
            float s1 = (i1 < 324) ? zp0[(long)cg * PX + pix1] : 0.f;
#pragma unroll
            for (int q = 0; q < 9; q++) {
                s0 = fmaf(wy[q], yw0[q], s0);
                s1 = fmaf(wy[q], yw1[q], s1);
            }
            zl[ch][i0] = in0_ ? fast_tanh(s0) : 0.f;
            if (i1 < 324) zl[ch][i1] = in1_ ? fast_tanh(s1) : 0.f;
        }
        __syncthreads();
        for (int ch = 0; ch < 16; ch++) {
            const float* wp = wt2 + (hf * 16 + ch) * 9;
#pragma unroll
            for (int ky = 0; ky < 3; ky++)
#pragma unroll
                for (int kx = 0; kx < 3; kx++)
                    sacc = fmaf(wp[ky * 3 + kx], zl[ch][(ty + ky) * 18 + tx + kx], sacc);
        }
    }
    score[((long)b * 10 + t) * PX + (long)(tileY + ty) * 128 + tileX + tx] = sacc;
}

// ============ fused softmax + temporal weighted sum, ch-group split ========
__global__ __launch_bounds__(256)
void smax_wsum_k(const float* __restrict__ score, const float* __restrict__ hs1,
                 float* __restrict__ aht, int rb, int nbs)
{
    const long idx = (long)blockIdx.x * 256 + threadIdx.x;
    if (idx >= (long)rb * PX) return;
    const long b = idx >> 14, p = idx & 16383;
    const int ch0 = blockIdx.y * 8;
    const float* base = score + b * 10 * PX + p;
    float v[10]; float m = -1e30f;
#pragma unroll
    for (int t = 0; t < 10; t++) { v[t] = base[t * PX]; m = fmaxf(m, v[t]); }
    float sum = 0.f;
#pragma unroll
    for (int t = 0; t < 10; t++) { v[t] = fast_exp(v[t] - m); sum += v[t]; }
    const float r = __builtin_amdgcn_rcpf(sum);
#pragma unroll
    for (int t = 0; t < 10; t++) v[t] *= r;
    const long slot1 = (long)nbs * 64 * PX;
#pragma unroll
    for (int j = 0; j < 8; j++) {
        const int ch = ch0 + j;
        float a = 0.f;
#pragma unroll
        for (int t = 0; t < 10; t++)
            a += v[t] * hs1[t * slot1 + (b * 64 + ch) * PX + p];
        aht[(b * 64 + ch) * PX + p] = a;
    }
}

// ---------------------------------------------------------------------------
extern "C" void kernel_launch(void* const* d_in, const int* in_sizes, int n_in,
                              void* d_out, int out_size, void* d_ws, size_t ws_size,
                              hipStream_t stream)
{
    const float* x      = (const float*)d_in[0];
    const float* h0     = (const float*)d_in[1];
    const float* c0in   = (const float*)d_in[2];
    const float* h1     = (const float*)d_in[3];
    const float* c1     = (const float*)d_in[4];
    const float* w_enc0 = (const float*)d_in[5];
    const float* b_enc0 = (const float*)d_in[6];
    const float* w_enc1 = (const float*)d_in[7];
    const float* b_enc1 = (const float*)d_in[8];
    const float* w_dec0 = (const float*)d_in[9];
    const float* b_dec0 = (const float*)d_in[10];
    const float* w_dec1 = (const float*)d_in[11];
    const float* b_dec1 = (const float*)d_in[12];
    const float* wa1 = (const float*)d_in[13];
    const float* ba1 = (const float*)d_in[14];
    const float* wa2 = (const float*)d_in[15];
    const float* ba2 = (const float*)d_in[16];
    const float* wt1 = (const float*)d_in[17];
    const float* bt1 = (const float*)d_in[18];
    const float* wt2 = (const float*)d_in[19];
    const float* bt2 = (const float*)d_in[20];
    float* out = (float*)d_out;

    // ---- adaptive batch tile: need = (160 + 1188*nb)*PX*4 B ----
    // Extended tiers probe ws upward; remainder groups handled via rb.
    const int tiers[7] = {8, 6, 5, 4, 3, 2, 1};
    int nb = 0;
    for (int ti = 0; ti < 7; ti++) {
        const size_t need = (size_t)(160 + 1188 * tiers[ti]) * PX * sizeof(float);
        if (need <= ws_size) { nb = tiers[ti]; break; }
    }
    if (nb == 0) return;

    float* ws = (float*)d_ws;
    float* hs0 = ws;                      // [10][8][PX]
    float* cs0 = hs0 + 80 * PX;           // [10][8][PX]
    float* G   = cs0 + 80 * PX;
    // phase-1 aliases inside G
    float* A    = G;                      // [8][10][PX]
    float* sc1  = G + 80 * PX;            // [8][10][PX]
    // phase-2 per-group layout inside G (strides use nb)
    const long slot1  = (long)nb * 64 * PX;
    float* hs1   = G;                                 // 10 * slot1
    float* cs1   = hs1 + 10 * slot1;                  // 2 * slot1 (ping-pong)
    float* zpart = cs1 + 2 * slot1;                   // [10][nb][32][PX]
    float* aht   = zpart + (long)10 * nb * 32 * PX;   // [nb][64][PX]
    float* l1p   = aht + (long)nb * 64 * PX;          // [4][nb][4][PX]
    float* hs0g  = l1p + (long)4 * nb * 4 * PX;       // [5][nb][PX]
    float* cs0g  = hs0g + (long)5 * nb * PX;          // [5][nb][PX]
    float* scD   = cs0g + (long)5 * nb * PX;          // [nb][10][PX]

    const dim3 blk(256);
    const long TDP = (long)T_ * D_ * PX;
    const long zslot = (long)nb * 32 * PX;

    // ================= phase 1: encoder layer 0, FULL batch =================
    for (int t = 0; t < 10; t++) {
        const float* hprev = (t == 0) ? h0 : hs0 + (long)(t - 1) * 8 * PX;
        const float* cprev = (t == 0) ? c0in : cs0 + (long)(t - 1) * 8 * PX;
        iattn_k<<<dim3(64, 1, 80), blk, 0, stream>>>(
            x, (t == 0) ? nullptr : A, hprev, cprev, wa1, ba1, wa2, ba2, sc1);
        softmax_mul_k<<<512, blk, 0, stream>>>(sc1, A, 8, t == 0);
        enc0_lstm_k<<<dim3(64, 1, 8), blk, 0, stream>>>(
            x, t, A, hprev, cprev, w_enc0, b_enc0,
            hs0 + (long)t * 8 * PX, cs0 + (long)t * 8 * PX);
    }

    // ================= phase 2: per batch-group =================
    for (int b0 = 0; b0 < 8; b0 += nb) {
        const int rb = (8 - b0 < nb) ? (8 - b0) : nb;
        const float* xb  = x + (long)b0 * TDP;
        float* outb = out + (long)b0 * 5 * PX;

        // -------- encoder layer 1, with zpart(t-1) merged in ---------------
        for (int t = 0; t < 10; t++) {
            const float* hprev = (t == 0) ? h1 + (long)b0 * 64 * PX
                                          : hs1 + (long)(t - 1) * slot1;
            const float* cprev = (t == 0) ? c1 + (long)b0 * 64 * PX
                                          : cs1 + (long)((t - 1) & 1) * slot1;
            const int gx = (t == 0) ? 1024 : 1280;
            lstm_merge_k<<<dim3(gx, 1, rb), blk, 0, stream>>>(
                hs0 + (long)t * 8 * PX + (long)b0 * PX, PX,
                hprev, w_enc1, b_enc1, cprev,
                hs1 + (long)t * slot1, cs1 + (long)(t & 1) * slot1,
                (t == 0) ? nullptr : hs1 + (long)(t - 1) * slot1,
                (t == 0) ? nullptr : cs1 + (long)((t - 1) & 1) * slot1,
                (t == 0) ? nullptr : zpart + (long)(t - 1) * zslot,
                wt1, bt1);
        }
        zpart_k<<<dim3(64, 4, rb), blk, 0, stream>>>(
            hs1 + 9L * slot1, cs1 + slot1, zpart + 9L * zslot, wt1, bt1);

        // -------- decoder (5 steps) --------
        for (int s = 0; s < 5; s++) {
            const float* yptr; long ybs;
            if (s == 0) { yptr = xb + 9L * D_ * PX; ybs = TDP; }
            else        { yptr = hs0g + (long)(s - 1) * nb * PX; ybs = PX; }
            const float* hb1 = (s == 0) ? hs0 + 9L * 8 * PX + (long)b0 * PX
                                        : hs0g + (long)(s - 1) * nb * PX;
            const float* cb1 = (s == 0) ? cs0 + 9L * 8 * PX + (long)b0 * PX
                                        : cs0g + (long)(s - 1) * nb * PX;

            attn_fuse_k<<<dim3(64, 1, 10 * rb), blk, 0, stream>>>(
                yptr, ybs, zpart, wt1, wt2, bt2, scD, rb, nb);
            smax_wsum_k<<<dim3((int)(((long)rb * PX + 255) / 256), 8), blk, 0, stream>>>(
                scD, hs1, aht, rb, nb);

            // decoder LSTM 0 (no merged zpart: it depends on this kernel)
            lstm_merge_k<<<dim3(1024, 1, rb), blk, 0, stream>>>(
                yptr, ybs, aht, w_dec0, b_dec0,
                cs1 + (long)((s + 1) & 1) * slot1,
                hs1 + (long)s * slot1, cs1 + (long)(s & 1) * slot1,
                nullptr, nullptr, nullptr, wt1, bt1);

            // dec LSTM1 split-K conv + zpart(s) (skip zpart at s=4)
            const int gx2 = (s < 4) ? 512 : 256;
            dec_merge_k<<<dim3(gx2, 1, rb), blk, 0, stream>>>(
                hs1 + (long)s * slot1, hb1, PX, w_dec1, l1p, nb,
                cs1 + (long)(s & 1) * slot1, zpart + (long)s * zslot, wt1, bt1);
            combine_lstm_k<<<(int)(((long)rb * PX + 255) / 256), blk, 0, stream>>>(
                l1p, 4, 1, b_dec1, cb1, PX,
                hs0g + (long)s * nb * PX, PX,
                cs0g + (long)s * nb * PX, PX,
                outb + (long)s * PX, 5 * PX, rb, nb);
        }
    }
}